// Round 1
// baseline (483.781 us; speedup 1.0000x reference)
//
#include <hip/hip_runtime.h>

namespace {
constexpr int NBb = 8;                 // n_batch after /T
constexpr int TT  = 8;                 // T
constexpr int TOo = 8;                 // T_OUT
constexpr int CC  = 256;
constexpr int GG  = 4;
constexpr int CPG = 64;
constexpr int HHH = 56;
constexpr int WWW = 56;
constexpr int HWs = HHH * WWW;         // 3136
constexpr long CHW = (long)CC * HWs;   // 802816
constexpr int NC  = (TT - 1) * 9;      // 63
}

__global__ __launch_bounds__(64, 2)
void corr_fusion(const float* __restrict__ x,
                 const float* __restrict__ conv_w,
                 const float* __restrict__ conv_b,
                 float* __restrict__ out)
{
    const int w  = threadIdx.x;                  // lane = w (0..63, active w<56)
    const int wc = w < WWW - 1 ? w : WWW - 1;    // clamped for addressing
    const int h  = blockIdx.x;
    const int g  = blockIdx.y;
    const int n  = blockIdx.z;
    const int hm = h > 0 ? h - 1 : 0;            // replication pad vertical
    const int hp = h < HHH - 1 ? h + 1 : HHH - 1;

    const int offh = h  * WWW + wc;
    const int offm = hm * WWW + wc;
    const int offp = hp * WWW + wc;

    // ---------------- phase 1: 9-way shifted correlation ----------------
    // corr[t*9 + i*3 + j] = sum_c x[t, gc, h, w] * x[t+1, gc, h+i-1, w+j-1] (clamped)
    float corr[NC];
#pragma unroll
    for (int i = 0; i < NC; ++i) corr[i] = 0.0f;

    const float* xg = x + (long)n * TT * CHW + (long)g * CPG * HWs;

    for (int c = 0; c < CPG; ++c) {
        const float* xc = xg + (long)c * HWs;
        float rh[TT], rm[TT - 1], rp[TT - 1];
#pragma unroll
        for (int t = 0; t < TT; ++t) rh[t] = xc[(long)t * CHW + offh];
#pragma unroll
        for (int t = 1; t < TT; ++t) {
            rm[t - 1] = xc[(long)t * CHW + offm];
            rp[t - 1] = xc[(long)t * CHW + offp];
        }
#pragma unroll
        for (int t = 0; t < TT - 1; ++t) {
            const float a = rh[t];
#pragma unroll
            for (int di = 0; di < 3; ++di) {
                float bc = (di == 0) ? rm[t] : (di == 1) ? rh[t + 1] : rp[t];
                float bl = __shfl_up(bc, 1);     // value at w-1
                if (w == 0) bl = bc;             // replication pad left
                float br = __shfl_down(bc, 1);   // value at w+1
                if (w == WWW - 1) br = bc;       // replication pad right
                const int base = t * 9 + di * 3;
                corr[base + 0] = fmaf(a, bl, corr[base + 0]);
                corr[base + 1] = fmaf(a, bc, corr[base + 1]);
                corr[base + 2] = fmaf(a, br, corr[base + 2]);
            }
        }
    }

    // ---------------- grouped 1x1 conv: corr[63] -> wx[64] ----------------
    // conv_w: (G, 64, 63); all lanes read same element -> scalar loads
    const float* cw = conv_w + (long)g * (TOo * TT) * NC;
    const float* cb = conv_b + g * (TOo * TT);
    float wx[TOo * TT];
#pragma unroll
    for (int o = 0; o < TOo * TT; ++o) {
        float s = cb[o];
#pragma unroll
        for (int i = 0; i < NC; ++i) s = fmaf(cw[o * NC + i], corr[i], s);
        wx[o] = s;
    }

    // ---------------- phase 2: weighted segment-sum + residual ----------------
    // out[n*8+to, g*64+cp, h, w] = sum_t wx[to*8+t] * x[n*8+t, cp*4+g, h, w]
    //                            + x[n*8+to, cp*4+g, h, w]
    const float* xn = x   + (long)n * TT  * CHW;
    float*       on = out + (long)n * TOo * CHW;
    for (int cp = 0; cp < CPG; ++cp) {
        const float* xc = xn + (long)(cp * GG + g) * HWs + offh;
        float xv[TT];
#pragma unroll
        for (int t = 0; t < TT; ++t) xv[t] = xc[(long)t * CHW];
        if (w < WWW) {
            float* oc = on + (long)(g * CPG + cp) * HWs + h * WWW + w;
#pragma unroll
            for (int to = 0; to < TOo; ++to) {
                float s = xv[to];   // residual (i_in[to] == to)
#pragma unroll
                for (int t = 0; t < TT; ++t) s = fmaf(wx[to * TT + t], xv[t], s);
                oc[(long)to * CHW] = s;
            }
        }
    }
}

extern "C" void kernel_launch(void* const* d_in, const int* in_sizes, int n_in,
                              void* d_out, int out_size, void* d_ws, size_t ws_size,
                              hipStream_t stream) {
    const float* x  = (const float*)d_in[0];
    const float* cw = (const float*)d_in[1];
    const float* cb = (const float*)d_in[2];
    float* out = (float*)d_out;

    dim3 grid(HHH, GG, NBb);   // (h, g, n) = (56, 4, 8) -> 1792 single-wave blocks
    dim3 block(64);
    hipLaunchKernelGGL(corr_fusion, grid, block, 0, stream, x, cw, cb, out);
}